// Round 10
// baseline (154.324 us; speedup 1.0000x reference)
//
#include <hip/hip_runtime.h>

// LoopHead: node MLP (32->64->32) then edge decoder (gather/concat -> 64 -> 1)
// Wire dtypes per the reference: fp32 tensors, int32 edge_index, fp32 out.
// R10 = R9 (proven) + (a) persistent biasC as the MFMA C-operand — removes
// the per-iteration accumulator-init moves; (b) __launch_bounds__(256,4) on
// the edge kernel to force the allocator under 128 unified regs -> 4
// waves/SIMD. Structure otherwise identical to R9 (2 tiles, index prefetch).

typedef short bfrag4 __attribute__((ext_vector_type(4)));  // 4 bf16 (x16 frag)
typedef short s16x8  __attribute__((ext_vector_type(8)));  // 8 bf16 (x32 frag)
typedef float f32x4v __attribute__((ext_vector_type(4)));  // fp32 x4

#define N_NODES 100000
#define N_EDGES 3200000

__device__ __forceinline__ unsigned short f2bf(float f) {
    unsigned int i = __float_as_uint(f);
    unsigned int r = i + 0x7FFFu + ((i >> 16) & 1u);  // RNE
    return (unsigned short)(r >> 16);
}

__device__ __forceinline__ bfrag4 cvt4(float x0, float x1, float x2, float x3) {
    bfrag4 v;
    v[0] = (short)f2bf(x0);
    v[1] = (short)f2bf(x1);
    v[2] = (short)f2bf(x2);
    v[3] = (short)f2bf(x3);
    return v;
}

// ---------------- Kernel 1: node projection -> z_loop (bf16 [N,32]) --------
// (verbatim round-3/6/7/9 version — proven through all harness checks)
__global__ __launch_bounds__(256) void node_proj_kernel(
    const float* __restrict__ z_mod,   // [N,32] fp32
    const float* __restrict__ w1,      // [32,64] row-major (k,n)
    const float* __restrict__ b1,      // [64]
    const float* __restrict__ w2,      // [64,32] row-major (k,n)
    const float* __restrict__ b2,      // [32]
    unsigned short* __restrict__ z_loop)  // [N,32] bf16 out (workspace)
{
    __shared__ unsigned short hbuf[4][16 * 72];

    const int tid  = threadIdx.x;
    const int wave = tid >> 6;
    const int lane = tid & 63;
    const int quad = lane >> 4;
    const int col  = lane & 15;

    bfrag4 bw1[2][4];   // stage 1: K=32 (2 steps), N=64 (4 n-tiles)
    float  bias1[4];
    for (int t = 0; t < 4; ++t) {
        const int n = col + 16 * t;
        for (int s = 0; s < 2; ++s)
            for (int j = 0; j < 4; ++j)
                bw1[s][t][j] = (short)f2bf(w1[(s * 16 + quad * 4 + j) * 64 + n]);
        bias1[t] = b1[n];
    }
    bfrag4 bw2[4][2];   // stage 2: K=64 (4 steps), N=32 (2 n-tiles)
    float  bias2[2];
    for (int t = 0; t < 2; ++t) {
        const int n = col + 16 * t;
        for (int s = 0; s < 4; ++s)
            for (int j = 0; j < 4; ++j)
                bw2[s][t][j] = (short)f2bf(w2[(s * 16 + quad * 4 + j) * 32 + n]);
        bias2[t] = b2[n];
    }

    unsigned short* hrow = &hbuf[wave][0];

    const int gwave  = blockIdx.x * 4 + wave;
    const int nwaves = gridDim.x * 4;
    const int ntiles = N_NODES / 16;   // 6250, exact

    for (int tile = gwave; tile < ntiles; tile += nwaves) {
        const int node0 = tile * 16;
        const float* zrow = z_mod + (size_t)(node0 + col) * 32;

        f32x4v za0 = *(const f32x4v*)(zrow + 0 * 16 + quad * 4);
        f32x4v za1 = *(const f32x4v*)(zrow + 1 * 16 + quad * 4);
        bfrag4 a10 = cvt4(za0[0], za0[1], za0[2], za0[3]);
        bfrag4 a11 = cvt4(za1[0], za1[1], za1[2], za1[3]);

        f32x4v acc[4];
        for (int t = 0; t < 4; ++t) {
            f32x4v c = {bias1[t], bias1[t], bias1[t], bias1[t]};
            c = __builtin_amdgcn_mfma_f32_16x16x16bf16_1k(a10, bw1[0][t], c, 0, 0, 0);
            c = __builtin_amdgcn_mfma_f32_16x16x16bf16_1k(a11, bw1[1][t], c, 0, 0, 0);
            acc[t] = c;
        }

        for (int t = 0; t < 4; ++t)
            for (int r = 0; r < 4; ++r) {
                float v = acc[t][r];
                v = v > 0.f ? v : 0.f;
                hrow[(quad * 4 + r) * 72 + (col + 16 * t)] = f2bf(v);
            }
        asm volatile("" ::: "memory");

        f32x4v acc2[2];
        for (int t = 0; t < 2; ++t)
            acc2[t] = (f32x4v){bias2[t], bias2[t], bias2[t], bias2[t]};
        for (int s = 0; s < 4; ++s) {
            bfrag4 a2 = *(const bfrag4*)(hrow + col * 72 + s * 16 + quad * 4);
            for (int t = 0; t < 2; ++t)
                acc2[t] = __builtin_amdgcn_mfma_f32_16x16x16bf16_1k(a2, bw2[s][t], acc2[t], 0, 0, 0);
        }
        asm volatile("" ::: "memory");

        for (int t = 0; t < 2; ++t)
            for (int r = 0; r < 4; ++r)
                z_loop[(size_t)(node0 + quad * 4 + r) * 32 + (col + 16 * t)] =
                    f2bf(acc2[t][r]);
    }
}

// ---------------- Kernel 2: edge decoder (R9 + biasC + occupancy bound) -----
__global__ __launch_bounds__(256, 4) void edge_dec_kernel(
    const int*            __restrict__ eidx,     // [2, E] int32
    const unsigned short* __restrict__ z_loop,   // [N,32] bf16
    const float*          __restrict__ dw1,      // [64,64] row-major (k,n)
    const float*          __restrict__ db1,      // [64]
    const float*          __restrict__ dw2,      // [64]
    const float*          __restrict__ db2,      // [1]
    float* __restrict__ out)                     // [E] fp32
{
    const int tid  = threadIdx.x;
    const int lane = tid & 63;
    const int quad = lane >> 4;
    const int col  = lane & 15;

    // A-frags = dw1^T tiles: aw[s][mt] holds A[m=16mt+col][k=32s+quad*8+j]
    s16x8 aw[2][4];
    f32x4v biasC[4];     // persistent C-operand: biasC[mt][r] = db1[16mt+quad*4+r]
    float  w2v[4][4];    // [mt][r] = dw2[16mt + quad*4 + r]
    for (int mt = 0; mt < 4; ++mt) {
        const int h = 16 * mt + col;
        for (int s = 0; s < 2; ++s)
            for (int j = 0; j < 8; ++j)
                aw[s][mt][j] = (short)f2bf(dw1[(32 * s + quad * 8 + j) * 64 + h]);
        for (int r = 0; r < 4; ++r) {
            biasC[mt][r] = db1[16 * mt + quad * 4 + r];
            w2v[mt][r]   = dw2[16 * mt + quad * 4 + r];
        }
    }
    const float bias2 = db2[0];

    const int gwave  = blockIdx.x * 4 + (tid >> 6);
    const int nwaves = gridDim.x * 4;
    const int npairs = N_EDGES / 32;   // 100000, exact (2 tiles of 16 per iter)

    // prefetch indices for the first iteration (nwaves = 6144 <= npairs)
    int sA = eidx[gwave * 32 + col];
    int sB = eidx[gwave * 32 + 16 + col];
    int dA = eidx[N_EDGES + gwave * 32 + col];
    int dB = eidx[N_EDGES + gwave * 32 + 16 + col];

    for (int p = gwave; p < npairs; p += nwaves) {
        const int e0 = p * 32;

        // 4 independent 16B gathers — each IS a B-fragment
        // (B[k=quad*8+j][n=col]); issued first, consumed after the prefetch.
        s16x8 gA0 = *(const s16x8*)(z_loop + (size_t)sA * 32 + quad * 8);
        s16x8 gA1 = *(const s16x8*)(z_loop + (size_t)dA * 32 + quad * 8);
        s16x8 gB0 = *(const s16x8*)(z_loop + (size_t)sB * 32 + quad * 8);
        s16x8 gB1 = *(const s16x8*)(z_loop + (size_t)dB * 32 + quad * 8);

        // prefetch NEXT iteration's indices (branchless clamp, always valid)
        const int pn = p + nwaves;
        const int pc = pn < npairs ? pn : gwave;
        sA = eidx[pc * 32 + col];
        sB = eidx[pc * 32 + 16 + col];
        dA = eidx[N_EDGES + pc * 32 + col];
        dB = eidx[N_EDGES + pc * 32 + 16 + col];

        // he^T[m=hidden][n=edge]: first MFMA of each pair reads the
        // persistent biasC as C — no per-iteration accumulator init.
        f32x4v accA[4], accB[4];
        for (int mt = 0; mt < 4; ++mt) {
            f32x4v c = __builtin_amdgcn_mfma_f32_16x16x32_bf16(aw[0][mt], gA0, biasC[mt], 0, 0, 0);
            accA[mt] = __builtin_amdgcn_mfma_f32_16x16x32_bf16(aw[1][mt], gA1, c, 0, 0, 0);
        }
        for (int mt = 0; mt < 4; ++mt) {
            f32x4v c = __builtin_amdgcn_mfma_f32_16x16x32_bf16(aw[0][mt], gB0, biasC[mt], 0, 0, 0);
            accB[mt] = __builtin_amdgcn_mfma_f32_16x16x32_bf16(aw[1][mt], gB1, c, 0, 0, 0);
        }

        // relu + dw2-dot: lane owns 16 hidden units of ONE edge (n=col);
        // in-lane fma then 2-step quad reduce.
        float pA = 0.f, pB = 0.f;
        for (int mt = 0; mt < 4; ++mt)
            for (int r = 0; r < 4; ++r) {
                float vA = accA[mt][r]; vA = vA > 0.f ? vA : 0.f;
                float vB = accB[mt][r]; vB = vB > 0.f ? vB : 0.f;
                pA += vA * w2v[mt][r];
                pB += vB * w2v[mt][r];
            }
        pA += __shfl_xor(pA, 16, 64);
        pA += __shfl_xor(pA, 32, 64);
        pB += __shfl_xor(pB, 16, 64);
        pB += __shfl_xor(pB, 32, 64);

        // lanes 0-15: edge e0+lane (tile A); 16-31: e0+lane (tile B).
        if (lane < 32) {
            float v = (lane < 16 ? pA : pB) + bias2;
            out[e0 + lane] = v;
        }
    }
}

extern "C" void kernel_launch(void* const* d_in, const int* in_sizes, int n_in,
                              void* d_out, int out_size, void* d_ws, size_t ws_size,
                              hipStream_t stream) {
    const float* z_mod = (const float*)d_in[0];
    const int*   eidx  = (const int*)d_in[1];
    const float* w1    = (const float*)d_in[2];
    const float* b1    = (const float*)d_in[3];
    const float* w2    = (const float*)d_in[4];
    const float* b2    = (const float*)d_in[5];
    const float* dw1   = (const float*)d_in[6];
    const float* db1   = (const float*)d_in[7];
    const float* dw2   = (const float*)d_in[8];
    const float* db2   = (const float*)d_in[9];
    float*          out    = (float*)d_out;
    unsigned short* z_loop = (unsigned short*)d_ws;   // 100000*32*2B = 6.4 MB

    node_proj_kernel<<<512, 256, 0, stream>>>(z_mod, w1, b1, w2, b2, z_loop);
    edge_dec_kernel<<<1536, 256, 0, stream>>>(eidx, z_loop, dw1, db1, dw2, db2, out);
}